// Round 13
// baseline (1661.696 us; speedup 1.0000x reference)
//
#include <hip/hip_runtime.h>
#include <math.h>

// FISTA, phase-split 4x, TWO-CHAIN INTERLEAVE — R30.
// R28/R29 post-mortem: two bench exceptions with zero dispatches; both
// shared the sc0-inline-asm/XCC-id surface -> abandoned. Only R23-R27
// proven primitives here (agent atomics, counter exchange).
// R26 budget re-derivation: 11,466 cyc/iter = ~2,600 VALU(critical SIMD)
// + ~2,300 exchange + ~6,500 WAITING (barriers, L3 RTT exposure, skew).
// 80% latency-bound with zero TLP (1 block/CU, all waves co-stall). Fix:
// each CU interleaves TWO independent FISTA chains so one chain's compute
// covers the other's exchange latency.
//  - 128 blocks; block b: chain A = image nA=b&31, chain B = image
//    nB=32+(b&31); same group g=b>>5 for both (shared conv-weight slice).
//  - Image m<32: its 4 partials all produced at STEP 1 (blocks m+32g);
//    image m>=32: all at STEP 2. Schedule per iter:
//      stage1(A); S1(drain); addA;          // fire-and-forget
//      stage1(B);                           // covers A's drain+add RTT
//      S2(drain); addB; spinA;              // A's adds ~2,600cy old -> ~0 wait
//      S3; prepassA; S4; beta; stage2A;     // covers B's add RTT
//      S5; spinB; S6; prepassB; S7; stage2B; S8.
//  - WAR audit per chain (R26 verbatim): spinX(j) => all 4 addX(j) =>
//    their prepassX(j-1) (program order); stage1X(j+1) follows spinX(j);
//    buffers double-rotated (iter&1). Deadlock-free: adds unconditional.
// Arithmetic per element identical to R26 -> bit-identical output.
//
// Kept verbatim from R23-R26 (955us lineage): conv weights in LDS
// [tap][lane][4] b128 (VGPR hoists spill/remat — R19/R21/R24); pk_fma
// stage-1; DPP(2)+stride-20 transpose reduce + ONE coalesced 27-lane
// atomic store; prepass r = x - a; Wct stride-200 b128; centralized
// tid0 add+spin counter exchange at agent scope.

#define ITERS 200
#define THREADS 576
// d_ws float offsets (R26 layout, ~593 KB)
#define WGOFF 0          // 19200: [g][t*3+co][lane], q=3 lanes zeroed
#define WCTOFF 19200     // 600: [c(stride 200)][ci*64][p]
#define APOFF 19800      // 2 * 64 * 972 = 124416 (double-buffered)
#define CNTOFF 144256    // int offsets: 64 images x 64-int padding
// LDS float offsets
#define LWG 0            // conv weights: 25 taps x 64 lanes x 4 = 6400
#define LWCT 6400        // Wct: 600
#define LT 7000          // transpose scratch: 9 waves x 540
#define LYA 11860        // y(A): 3888
#define LYLA 15748       // y_last(A): 3888
#define LAA 19636        // r(A): 243 (+1 pad)
#define LXSA 19880       // x(A): 243 (+1 pad)
#define LYB 20124        // y(B): 3888
#define LYLB 24012       // y_last(B): 3888
#define LAB 27900        // r(B): 243 (+1 pad)
#define LXSB 28144       // x(B): 243 (+1 pad)
#define SMEMF 28388      // 113,552 B

typedef float f32x2 __attribute__((ext_vector_type(2)));

template <int CTRL>
__device__ __forceinline__ float dpp_add(float x) {
  int moved = __builtin_amdgcn_update_dpp(0, __float_as_int(x), CTRL, 0xF, 0xF, true);
  return x + __int_as_float(moved);
}

// WG[((g*75 + t*3 + co))*64 + lane] = w_conv[8*th+ph][8*tw+pw][ci=q][co]
//   with lane=(q,pl), p = g*16+pl; q==3 -> 0 (dead quadrant).
// WCT2[c*200 + ci*64 + p] = (rh<5 && rw<5) ? w_ct[4-rh][4-rw][ci][c] : 0.
__global__ void k0_init(const float* __restrict__ w_conv,
                        const float* __restrict__ w_ct,
                        float* __restrict__ ws) {
  const int i = blockIdx.x * 256 + threadIdx.x;
  if (i < 19200) {
    const int lane = i & 63;
    const int rest = i >> 6;          // g*75 + t*3 + co
    const int g = rest / 75;
    const int tc = rest - 75 * g;
    const int t = tc / 3;
    const int co = tc - 3 * t;
    const int th = t / 5;
    const int tw = t - 5 * th;
    const int q = lane >> 4;
    const int pl = lane & 15;
    float v = 0.f;
    if (q < 3) {
      const int p = g * 16 + pl;
      const int ph = p >> 3;
      const int pw = p & 7;
      v = w_conv[(((8 * th + ph) * 40 + (8 * tw + pw)) * 3 + q) * 3 + co];
    }
    ws[WGOFF + i] = v;
  }
  if (i < 600) {
    const int c = i / 200;
    const int rem = i - 200 * c;
    float v = 0.f;
    if (rem < 192) {
      const int ci = rem >> 6;
      const int p = rem & 63;
      const int rh = p >> 3;
      const int rw = p & 7;
      if (rh < 5 && rw < 5) v = w_ct[(((4 - rh) * 5 + (4 - rw)) * 3 + ci) * 3 + c];
    }
    ws[WCTOFF + i] = v;
  }
  if (i < 4096) ((int*)ws)[CNTOFF + i] = 0;
}

// ---- chain helpers (R26 bodies, parameterized by LDS bases / image) ----

__device__ __forceinline__ void stage1_one(
    float* smem, float* ws, int LYbase, int n, int g, int iter,
    int oh, int lane, int wid, int ylane) {
  f32x2 a01[9];                // [ow] = (co0, co1)
  float a2[9];                 // [ow] = co2
#pragma unroll
  for (int k = 0; k < 9; ++k) { a01[k].x = 0.f; a01[k].y = 0.f; a2[k] = 0.f; }

#pragma unroll
  for (int th = 0; th < 5; ++th) {
    const int r = oh + th - 2;          // input row
    if (r >= 0 && r <= 8) {
      f32x2 y2[9];                      // broadcast pairs {y,y}
#pragma unroll
      for (int wc = 0; wc < 9; ++wc) {
        const float yv = smem[LYbase + r * 432 + wc * 48 + ylane];
        y2[wc].x = yv; y2[wc].y = yv;
      }
#pragma unroll
      for (int tw = 0; tw < 5; ++tw) {
        const float4 wv =
            *(const float4*)&smem[LWG + ((th * 5 + tw) * 64 + lane) * 4];
        f32x2 w01; w01.x = wv.x; w01.y = wv.y;
#pragma unroll
        for (int ow = 0; ow < 9; ++ow) {
          const int col = ow + tw - 2;
          if (col >= 0 && col <= 8) {   // compile-time trim
            a01[ow] += y2[col] * w01;   // v_pk_fma_f32
            a2[ow]  += y2[col].x * wv.z;
          }
        }
      }
    }
  }

  // reduce: 2 DPP stages -> 4-lane sums; stride-20 transpose; lanes<27
  // final sum; ONE coalesced 27-lane atomic store (R23-proven).
  float s4[27];
#pragma unroll
  for (int k = 0; k < 27; ++k) {
    const int ow = k / 3, co = k - 3 * ow;      // compile-time
    const float av = (co == 0) ? a01[ow].x : (co == 1) ? a01[ow].y : a2[ow];
    const float s1 = dpp_add<0x111>(av);        // row_shr:1
    s4[k] = dpp_add<0x112>(s1);                 // row_shr:2 -> 4-group sum
  }
  float* Tw = &smem[LT + wid * 540];
  if ((lane & 3) == 3) {
    const int m = lane >> 2;                    // 0..15
#pragma unroll
    for (int k = 0; k < 27; ++k) Tw[k * 20 + m] = s4[k];
  }
  asm volatile("s_waitcnt lgkmcnt(0)" ::: "memory");
  if (lane < 27) {
    const float4* Tr = (const float4*)&Tw[lane * 20];
    const float4 p0 = Tr[0];
    const float4 p1 = Tr[1];
    const float4 p2 = Tr[2];
    const float4 p3 = Tr[3];
    const float s01 = (p0.x + p0.y) + (p0.z + p0.w);
    const float s23 = (p1.x + p1.y) + (p1.z + p1.w);
    const float s45 = (p2.x + p2.y) + (p2.z + p2.w);
    const float s67 = (p3.x + p3.y) + (p3.z + p3.w);
    const float s = (s01 + s23) + (s45 + s67);
    float* ap = ws + APOFF + ((iter & 1) * 64 + n) * 972 + g * 243
                + oh * 27 + lane;
    __hip_atomic_store(ap, s, __ATOMIC_RELAXED, __HIP_MEMORY_SCOPE_AGENT);
  }
}

__device__ __forceinline__ void prepass_one(
    float* smem, const float* ws, int LAb, int LXSb, int n, int iter,
    int tid, float bcv) {
  if (tid < 243) {
    const float* ap = ws + APOFF + ((iter & 1) * 64 + n) * 972;
    const float a0 = __hip_atomic_load(ap + tid, __ATOMIC_RELAXED,
                                       __HIP_MEMORY_SCOPE_AGENT);
    const float a1 = __hip_atomic_load(ap + 243 + tid, __ATOMIC_RELAXED,
                                       __HIP_MEMORY_SCOPE_AGENT);
    const float a2v = __hip_atomic_load(ap + 486 + tid, __ATOMIC_RELAXED,
                                        __HIP_MEMORY_SCOPE_AGENT);
    const float a3 = __hip_atomic_load(ap + 729 + tid, __ATOMIC_RELAXED,
                                       __HIP_MEMORY_SCOPE_AGENT);
    smem[LAb + tid] = smem[LXSb + tid] - (a0 + a1 + a2v + a3 + bcv);
  }
}

__device__ __forceinline__ void stage2_one(
    float* smem, int LYb, int LYLb, int LAb, int tid, int cell, int c,
    int cb, int pb, float lam_n, float bct, float beta, bool lastit,
    float* out, int n) {
  if (tid < 486) {
    const float r0  = smem[LAb + cb + 0];
    const float r1  = smem[LAb + cb + 1];
    const float r2v = smem[LAb + cb + 2];

    const float4 w0a = *(const float4*)&smem[LWCT + c * 200 +   0 + pb];
    const float4 w0b = *(const float4*)&smem[LWCT + c * 200 +   4 + pb];
    const float4 w1a = *(const float4*)&smem[LWCT + c * 200 +  64 + pb];
    const float4 w1b = *(const float4*)&smem[LWCT + c * 200 +  68 + pb];
    const float4 w2a = *(const float4*)&smem[LWCT + c * 200 + 128 + pb];
    const float4 w2b = *(const float4*)&smem[LWCT + c * 200 + 132 + pb];
    const float wct0[8] = {w0a.x, w0a.y, w0a.z, w0a.w, w0b.x, w0b.y, w0b.z, w0b.w};
    const float wct1[8] = {w1a.x, w1a.y, w1a.z, w1a.w, w1b.x, w1b.y, w1b.z, w1b.w};
    const float wct2[8] = {w2a.x, w2a.y, w2a.z, w2a.w, w2b.x, w2b.y, w2b.z, w2b.w};

    float4* lyv  = (float4*)&smem[LYb];
    float4* lylv = (float4*)&smem[LYLb];
    const float4 y0 = lyv[2 * tid];
    const float4 y1 = lyv[2 * tid + 1];
    const float yv[8] = {y0.x, y0.y, y0.z, y0.w, y1.x, y1.y, y1.z, y1.w};
    float yn[8];
#pragma unroll
    for (int j = 0; j < 8; ++j) {
      const float re = bct + r0 * wct0[j] + r1 * wct1[j] + r2v * wct2[j];
      const float wvv = yv[j] - re;
      yn[j] = fmaxf(wvv - lam_n, 0.f) - fmaxf(-wvv - lam_n, 0.f);
    }

    if (!lastit) {
      const float4 l0 = lylv[2 * tid];
      const float4 l1 = lylv[2 * tid + 1];
      const float ylv[8] = {l0.x, l0.y, l0.z, l0.w, l1.x, l1.y, l1.z, l1.w};
      float4 s0, s1, m0, m1;
      s0.x = yn[0]; s0.y = yn[1]; s0.z = yn[2]; s0.w = yn[3];
      s1.x = yn[4]; s1.y = yn[5]; s1.z = yn[6]; s1.w = yn[7];
      m0.x = yn[0] + beta * (yn[0] - ylv[0]);
      m0.y = yn[1] + beta * (yn[1] - ylv[1]);
      m0.z = yn[2] + beta * (yn[2] - ylv[2]);
      m0.w = yn[3] + beta * (yn[3] - ylv[3]);
      m1.x = yn[4] + beta * (yn[4] - ylv[4]);
      m1.y = yn[5] + beta * (yn[5] - ylv[5]);
      m1.z = yn[6] + beta * (yn[6] - ylv[6]);
      m1.w = yn[7] + beta * (yn[7] - ylv[7]);
      lylv[2 * tid] = s0; lylv[2 * tid + 1] = s1;
      lyv[2 * tid]  = m0; lyv[2 * tid + 1]  = m1;
    } else {
      const int part = pb >> 3;           // p>>3 constant over j
      const int qh = cell / 9;
      const int qw = cell - 9 * qh;
      const int ih = 8 * qh + part;
      float* op = out + ((n * 72 + ih) * 72 + 8 * qw) * 3 + c;
#pragma unroll
      for (int j = 0; j < 8; ++j) op[3 * j] = yn[j];
    }
  }
}

__global__ __launch_bounds__(THREADS) void fista_split(
    float* __restrict__ ws,
    const float* __restrict__ x, const float* __restrict__ lam,
    const float* __restrict__ b_conv, const float* __restrict__ b_ct,
    float* __restrict__ out) {
  __shared__ __align__(16) float smem[SMEMF];
  const int tid = threadIdx.x;
  const int b = blockIdx.x;       // 0..127
  const int g = b >> 5;           // 0..3 (shared by both chains)
  const int nA = b & 31;          // images 0..31  (all partials at step 1)
  const int nB = 32 + (b & 31);   // images 32..63 (all partials at step 2)
  const int lane = tid & 63;
  const int wid = tid >> 6;       // wave index (9 waves)
  const int q = lane >> 4;        // ci quadrant (3 = dead)
  const int pl = lane & 15;
  const int ylane = ((q < 3) ? q : 2) * 16 + pl;  // q=3 dupes q=2: broadcast
  // wave->row perm {0,4,2,3,8,5,6,7,1}: per-SIMD tap-row load balanced (10).
  const int oh = (wid == 0) ? 0 : (wid == 1) ? 4 : (wid == 4) ? 8
               : (wid == 8) ? 1 : wid;

  int* __restrict__ cntA = (int*)ws + CNTOFF + nA * 64;
  int* __restrict__ cntB = (int*)ws + CNTOFF + nB * 64;
  const float lamA = lam[nA];
  const float lamB = lam[nB];
  const float bcv = b_conv[tid % 3];   // pre-pass bias (used when tid<243)
  const float bct0 = b_ct[0], bct1 = b_ct[1], bct2 = b_ct[2];

  // ---- stage LDS: zero all; scatter conv weights [tap][lane][4]; copy
  // Wct + both x slices ----
  for (int i = tid; i < SMEMF; i += THREADS) smem[i] = 0.f;
  __syncthreads();
  for (int i = tid; i < 4800; i += THREADS) {
    const int lane_i = i & 63;
    const int tc = i >> 6;            // t*3 + co
    const int t_i = tc / 3;
    const int co_i = tc - 3 * t_i;
    smem[LWG + (t_i * 64 + lane_i) * 4 + co_i] = ws[WGOFF + g * 4800 + i];
  }
  for (int i = tid; i < 600; i += THREADS) smem[LWCT + i] = ws[WCTOFF + i];
  if (tid < 243) {
    smem[LXSA + tid] = x[nA * 243 + tid];
    smem[LXSB + tid] = x[nB * 243 + tid];
  }
  __syncthreads();

  // stage-2 ownership: thread t<486 owns elements e = 8t .. 8t+7
  const int idx3 = tid >> 1;
  const int cell = idx3 / 3;
  const int c = idx3 - 3 * cell;
  const int cb = 3 * cell;
  const int plb = (tid & 1) * 8;       // p_local base (0 or 8)
  const int pb = g * 16 + plb;         // global p base
  const float bct = (c == 0) ? bct0 : ((c == 1) ? bct1 : bct2);

  float t = 1.0f;
#pragma unroll 1
  for (int iter = 0; iter < ITERS; ++iter) {
    const bool lastit = (iter == ITERS - 1);

    // ===== step 1: stage1(A); drain; EARLY addA (fire-and-forget) =====
    stage1_one(smem, ws, LYA, nA, g, iter, oh, lane, wid, ylane);
    __syncthreads();               // S1: all waves' A-stores drained (vmcnt)
    if (tid == 0)
      __hip_atomic_fetch_add(cntA, 1, __ATOMIC_RELAXED, __HIP_MEMORY_SCOPE_AGENT);

    // ===== step 2: stage1(B) — covers A's add RTT across blocks =====
    stage1_one(smem, ws, LYB, nB, g, iter, oh, lane, wid, ylane);
    __syncthreads();               // S2: B-stores drained
    if (tid == 0) {
      __hip_atomic_fetch_add(cntB, 1, __ATOMIC_RELAXED, __HIP_MEMORY_SCOPE_AGENT);
      const int target = 4 * (iter + 1);
      while (__hip_atomic_load(cntA, __ATOMIC_RELAXED, __HIP_MEMORY_SCOPE_AGENT)
             < target)            // A adds are ~1 stage-1 old -> near-zero wait
        __builtin_amdgcn_s_sleep(1);
    }
    __syncthreads();               // S3: image-A data confirmed

    // ===== chain A: prepass -> stage2 (covers B's add RTT) =====
    prepass_one(smem, ws, LAA, LXSA, nA, iter, tid, bcv);
    __syncthreads();               // S4: r(A) ready

    const float tn = (1.0f + sqrtf(1.0f + 4.0f * t * t)) * 0.5f;
    const float beta = (t - 1.0f) / tn;    // beta_0 = 0; shared by A and B
    t = tn;

    stage2_one(smem, LYA, LYLA, LAA, tid, cell, c, cb, pb, lamA, bct, beta,
               lastit, out, nA);
    __syncthreads();               // S5: y(A) stable

    // ===== chain B: spin (mostly elapsed) -> prepass -> stage2 =====
    if (tid == 0) {
      const int target = 4 * (iter + 1);
      while (__hip_atomic_load(cntB, __ATOMIC_RELAXED, __HIP_MEMORY_SCOPE_AGENT)
             < target)
        __builtin_amdgcn_s_sleep(1);
    }
    __syncthreads();               // S6: image-B data confirmed
    prepass_one(smem, ws, LAB, LXSB, nB, iter, tid, bcv);
    __syncthreads();               // S7: r(B) ready
    stage2_one(smem, LYB, LYLB, LAB, tid, cell, c, cb, pb, lamB, bct, beta,
               lastit, out, nB);
    __syncthreads();               // S8: y(B) stable before next stage-1
  }
}

extern "C" void kernel_launch(void* const* d_in, const int* in_sizes, int n_in,
                              void* d_out, int out_size, void* d_ws, size_t ws_size,
                              hipStream_t stream) {
  const float* x      = (const float*)d_in[0];
  const float* lam    = (const float*)d_in[1];
  const float* w_conv = (const float*)d_in[2];
  const float* b_conv = (const float*)d_in[3];
  const float* w_ct   = (const float*)d_in[4];
  const float* b_ct   = (const float*)d_in[5];
  float* out = (float*)d_out;
  float* ws  = (float*)d_ws;  // needs ~593 KB (R26 layout)

  hipLaunchKernelGGL(k0_init, dim3(80), dim3(256), 0, stream, w_conv, w_ct, ws);
  hipLaunchKernelGGL(fista_split, dim3(128), dim3(THREADS), 0, stream,
                     ws, x, lam, b_conv, b_ct, out);
}